// Round 2
// baseline (3109.452 us; speedup 1.0000x reference)
//
#include <hip/hip_runtime.h>
#include <math.h>

#define NN 50000
#define EE 640000
#define HD 128
#define ECD 64
#define NHD 4
#define HH 32
#define EPB 8   // edges per 256-thread block (32 lanes per edge)

__device__ __forceinline__ float ssp_f(float v) {
    // softplus(v) - log(2), numerically stable
    return fmaxf(v, 0.0f) + log1pf(expf(-fabsf(v))) - 0.69314718055994531f;
}

// order-preserving float<->uint mapping for atomicMax-based segment max
__device__ __forceinline__ unsigned int fmap(float f) {
    unsigned int u = __float_as_uint(f);
    return (u & 0x80000000u) ? ~u : (u | 0x80000000u);
}
__device__ __forceinline__ float funmap(unsigned int u) {
    return __uint_as_float((u & 0x80000000u) ? (u ^ 0x80000000u) : ~u);
}

// ---------------- K1: LN1 + per-head projections ----------------
__global__ __launch_bounds__(128) void k_node_prep(
    const float* __restrict__ x, const float* __restrict__ k_w,
    const float* __restrict__ q_w, const float* __restrict__ v_w,
    const float* __restrict__ ln1_g, const float* __restrict__ ln1_b,
    float* __restrict__ h_k, float* __restrict__ h_q, float* __restrict__ h_v)
{
    const int n = blockIdx.x;
    const int t = threadIdx.x;
    __shared__ float sy[HD];
    __shared__ float red[4];

    float xv = x[(size_t)n * HD + t];
    float s1 = xv, s2 = xv * xv;
    #pragma unroll
    for (int off = 32; off; off >>= 1) {
        s1 += __shfl_down(s1, off);
        s2 += __shfl_down(s2, off);
    }
    const int wid = t >> 6;
    if ((t & 63) == 0) { red[wid * 2] = s1; red[wid * 2 + 1] = s2; }
    __syncthreads();
    const float mean = (red[0] + red[2]) * (1.0f / HD);
    const float var  = (red[1] + red[3]) * (1.0f / HD) - mean * mean;
    const float rstd = rsqrtf(var + 1e-5f);
    const float y = (xv - mean) * rstd * ln1_g[t] + ln1_b[t];
    sy[t] = y;
    __syncthreads();

    const int h = t >> 5, k = t & 31;
    const float* syh = sy + h * HH;
    const float* kw = k_w + (size_t)(h * HH + k) * HH;
    const float* qw = q_w + (size_t)(h * HH + k) * HH;
    const float* vw = v_w + (size_t)(h * HH + k) * HH;
    float ak = 0.f, aq = 0.f, av = 0.f;
    #pragma unroll
    for (int d = 0; d < HH; ++d) {
        const float yv = syh[d];
        ak = fmaf(yv, kw[d], ak);
        aq = fmaf(yv, qw[d], aq);
        av = fmaf(yv, vw[d], av);
    }
    h_k[(size_t)n * HD + t] = ak;
    h_q[(size_t)n * HD + t] = aq;
    h_v[(size_t)n * HD + t] = av;
}

// ---------------- K2: per-edge qk + running max ----------------
__global__ __launch_bounds__(256) void k_edge_qk(
    const float* __restrict__ edge_attr, const int* __restrict__ edge_index,
    const float* __restrict__ h_k, const float* __restrict__ h_q,
    const float* __restrict__ wk1_w, const float* __restrict__ wk1_b,
    const float* __restrict__ wk2_w, const float* __restrict__ wk2_b,
    const float* __restrict__ wkl_w, const float* __restrict__ wkl_b,
    float* __restrict__ qk_out, unsigned int* __restrict__ m_map)
{
    const int g = threadIdx.x >> 5;
    const int l = threadIdx.x & 31;
    const int e = blockIdx.x * EPB + g;   // E % EPB == 0, no guard needed
    __shared__ float sEA[EPB][ECD];
    __shared__ float sBuf[EPB][HH];

    const float* ea = edge_attr + (size_t)e * ECD;
    sEA[g][l] = ea[l];
    sEA[g][l + 32] = ea[l + 32];
    const int row = edge_index[e];
    const int col = edge_index[EE + e];
    __syncthreads();

    // t1 = ssp(ea @ wk1_w.T + b1)
    float acc = wk1_b[l];
    const float* w1 = wk1_w + (size_t)l * ECD;
    #pragma unroll
    for (int c = 0; c < ECD; ++c) acc = fmaf(sEA[g][c], w1[c], acc);
    sBuf[g][l] = ssp_f(acc);
    __syncthreads();

    // Wk = t1 @ wk2_w.T + b2   (kept in register, only own lane needed later)
    float acc2 = wk2_b[l];
    const float* w2 = wk2_w + (size_t)l * HH;
    #pragma unroll
    for (int c = 0; c < HH; ++c) acc2 = fmaf(sBuf[g][c], w2[c], acc2);
    const float Wk_l = acc2;
    __syncthreads();   // protect sBuf before head-loop reuse

    for (int h = 0; h < NHD; ++h) {
        const float wkv = Wk_l * h_k[(size_t)col * HD + h * HH + l];
        sBuf[g][l] = wkv;
        __syncthreads();
        float key = wkl_b[l];
        const float* wl = wkl_w + (size_t)l * HH;
        #pragma unroll
        for (int c = 0; c < HH; ++c) key = fmaf(sBuf[g][c], wl[c], key);
        float p = key * h_q[(size_t)row * HD + h * HH + l];
        #pragma unroll
        for (int off = 16; off; off >>= 1) p += __shfl_xor(p, off, 32);
        if (l == 0) {
            qk_out[(size_t)e * NHD + h] = p;
            atomicMax(&m_map[row * NHD + h], fmap(p));
        }
        __syncthreads();
    }
}

// ---------------- K3: per-edge message + scatter-add ----------------
__global__ __launch_bounds__(256) void k_edge_msg(
    const float* __restrict__ edge_attr, const int* __restrict__ edge_index,
    const float* __restrict__ h_v,
    const float* __restrict__ wv1_w, const float* __restrict__ wv1_b,
    const float* __restrict__ wv2_w, const float* __restrict__ wv2_b,
    const float* __restrict__ wvl_w, const float* __restrict__ wvl_b,
    const float* __restrict__ qk, const unsigned int* __restrict__ m_map,
    float* __restrict__ denom, float* __restrict__ aggr)
{
    const int g = threadIdx.x >> 5;
    const int l = threadIdx.x & 31;
    const int e = blockIdx.x * EPB + g;
    __shared__ float sEA[EPB][ECD];
    __shared__ float sBuf[EPB][HH];

    const float* ea = edge_attr + (size_t)e * ECD;
    sEA[g][l] = ea[l];
    sEA[g][l + 32] = ea[l + 32];
    const int row = edge_index[e];
    const int col = edge_index[EE + e];
    __syncthreads();

    float acc = wv1_b[l];
    const float* w1 = wv1_w + (size_t)l * ECD;
    #pragma unroll
    for (int c = 0; c < ECD; ++c) acc = fmaf(sEA[g][c], w1[c], acc);
    sBuf[g][l] = ssp_f(acc);
    __syncthreads();

    float acc2 = wv2_b[l];
    const float* w2 = wv2_w + (size_t)l * HH;
    #pragma unroll
    for (int c = 0; c < HH; ++c) acc2 = fmaf(sBuf[g][c], w2[c], acc2);
    const float Wv_l = acc2;
    __syncthreads();

    for (int h = 0; h < NHD; ++h) {
        const float mv = Wv_l * h_v[(size_t)col * HD + h * HH + l];
        sBuf[g][l] = mv;
        __syncthreads();
        float msg = wvl_b[l];
        const float* wl = wvl_w + (size_t)l * HH;
        #pragma unroll
        for (int c = 0; c < HH; ++c) msg = fmaf(sBuf[g][c], wl[c], msg);
        const float mx = funmap(m_map[row * NHD + h]);
        const float ex = expf(qk[(size_t)e * NHD + h] - mx);
        atomicAdd(&aggr[(size_t)row * HD + h * HH + l], ex * msg);
        if (l == 0) atomicAdd(&denom[row * NHD + h], ex);
        __syncthreads();
    }
}

// ---------------- K4: normalize, residual, LN2, out matmul ----------------
__global__ __launch_bounds__(128) void k_node_out(
    const float* __restrict__ x, const float* __restrict__ aggr,
    const float* __restrict__ denom,
    const float* __restrict__ out_w, const float* __restrict__ out_b,
    const float* __restrict__ ln2_g, const float* __restrict__ ln2_b,
    float* __restrict__ out)
{
    const int n = blockIdx.x;
    const int t = threadIdx.x;
    const int h = t >> 5;
    __shared__ float sS[HD];
    __shared__ float red[4];

    const float den = denom[n * NHD + h];
    const float a = aggr[(size_t)n * HD + t];
    const float x2 = ((den > 0.0f) ? a / den : 0.0f) + x[(size_t)n * HD + t];

    float s1 = x2, s2 = x2 * x2;
    #pragma unroll
    for (int off = 32; off; off >>= 1) {
        s1 += __shfl_down(s1, off);
        s2 += __shfl_down(s2, off);
    }
    const int wid = t >> 6;
    if ((t & 63) == 0) { red[wid * 2] = s1; red[wid * 2 + 1] = s2; }
    __syncthreads();
    const float mean = (red[0] + red[2]) * (1.0f / HD);
    const float var  = (red[1] + red[3]) * (1.0f / HD) - mean * mean;
    const float rstd = rsqrtf(var + 1e-5f);
    const float y2 = (x2 - mean) * rstd * ln2_g[t] + ln2_b[t];
    sS[t] = ssp_f(y2);
    __syncthreads();

    float accum = out_b[t] + x2;
    const float* wrow = out_w + (size_t)t * HD;
    #pragma unroll 8
    for (int d = 0; d < HD; ++d) accum = fmaf(sS[d], wrow[d], accum);
    out[(size_t)n * HD + t] = accum;
}

extern "C" void kernel_launch(void* const* d_in, const int* in_sizes, int n_in,
                              void* d_out, int out_size, void* d_ws, size_t ws_size,
                              hipStream_t stream) {
    const float* x         = (const float*)d_in[0];
    const float* edge_attr = (const float*)d_in[1];
    const int*   edge_index= (const int*)  d_in[2];
    const float* k_w   = (const float*)d_in[3];
    const float* q_w   = (const float*)d_in[4];
    const float* v_w   = (const float*)d_in[5];
    const float* wk1_w = (const float*)d_in[6];
    const float* wk1_b = (const float*)d_in[7];
    const float* wk2_w = (const float*)d_in[8];
    const float* wk2_b = (const float*)d_in[9];
    const float* wkl_w = (const float*)d_in[10];
    const float* wkl_b = (const float*)d_in[11];
    const float* wv1_w = (const float*)d_in[12];
    const float* wv1_b = (const float*)d_in[13];
    const float* wv2_w = (const float*)d_in[14];
    const float* wv2_b = (const float*)d_in[15];
    const float* wvl_w = (const float*)d_in[16];
    const float* wvl_b = (const float*)d_in[17];
    const float* out_w = (const float*)d_in[18];
    const float* out_b = (const float*)d_in[19];
    const float* ln1_g = (const float*)d_in[20];
    const float* ln1_b = (const float*)d_in[21];
    const float* ln2_g = (const float*)d_in[22];
    const float* ln2_b = (const float*)d_in[23];

    float* ws = (float*)d_ws;
    float* h_k = ws;                                   // N*128
    float* h_q = h_k + (size_t)NN * HD;                // N*128
    float* h_v = h_q + (size_t)NN * HD;                // N*128
    float* qk  = h_v + (size_t)NN * HD;                // E*4
    unsigned int* m_map = (unsigned int*)(qk + (size_t)EE * NHD);  // N*4
    float* denom = (float*)(m_map + (size_t)NN * NHD); // N*4
    float* aggr  = denom + (size_t)NN * NHD;           // N*128

    (void)hipMemsetAsync(m_map, 0, (size_t)NN * NHD * sizeof(unsigned int), stream);
    (void)hipMemsetAsync(denom, 0, (size_t)NN * NHD * sizeof(float), stream);
    (void)hipMemsetAsync(aggr,  0, (size_t)NN * HD * sizeof(float), stream);

    k_node_prep<<<NN, 128, 0, stream>>>(x, k_w, q_w, v_w, ln1_g, ln1_b, h_k, h_q, h_v);
    k_edge_qk<<<EE / EPB, 256, 0, stream>>>(edge_attr, edge_index, h_k, h_q,
        wk1_w, wk1_b, wk2_w, wk2_b, wkl_w, wkl_b, qk, m_map);
    k_edge_msg<<<EE / EPB, 256, 0, stream>>>(edge_attr, edge_index, h_v,
        wv1_w, wv1_b, wv2_w, wv2_b, wvl_w, wvl_b, qk, m_map, denom, aggr);
    k_node_out<<<NN, 128, 0, stream>>>(x, aggr, denom, out_w, out_b, ln2_g, ln2_b,
        (float*)d_out);
}